// Round 1
// baseline (317.131 us; speedup 1.0000x reference)
//
#include <hip/hip_runtime.h>

// PointPillarScatter (B=4, C=64, 512x512x1 grid, P=120000)
// Strategy: invert scatter -> gather.
//   1) memset cell->pillar map (in d_ws) to -1           (4 MiB)
//   2) scatter: map[b*cells + cell] = p                  (tiny)
//   3) gather: out[b,c,cell] = map>=0 ? feat[p,c] : 0    (all stores coalesced)
// Output writes are the 256 MiB floor; gather reads of feat get 16x line
// reuse across the channel loop (L1-resident per block).

#define G_NX 512
#define G_NY 512
#define G_NZ 1
#define G_C 64
#define G_B 4
#define G_CELLS (G_NZ * G_NX * G_NY) // 262144

__global__ __launch_bounds__(256) void ppscatter_map_kernel(
    const int* __restrict__ coords, int* __restrict__ map, int P) {
  int p = blockIdx.x * blockDim.x + threadIdx.x;
  if (p >= P) return;
  int4 cr = ((const int4*)coords)[p]; // [b, z, y, x]
  int cell = cr.y + cr.z * G_NX + cr.w;
  map[cr.x * G_CELLS + cell] = p;
}

// grid: (CELLS/1024, B), block: 256 threads.
// Each thread: 4 consecutive cells, all 64 channels -> float4 store per c.
__global__ __launch_bounds__(256) void ppscatter_gather_kernel(
    const float* __restrict__ feat, const int* __restrict__ map,
    float* __restrict__ out) {
  const int b = blockIdx.y;
  const int cell0 = blockIdx.x * 1024 + threadIdx.x * 4;

  const int* mrow = map + b * G_CELLS;
  int4 p4 = *(const int4*)(mrow + cell0);

  float* orow = out + (size_t)b * G_C * G_CELLS + cell0;

#pragma unroll 8
  for (int c = 0; c < G_C; ++c) {
    float4 v;
    v.x = (p4.x >= 0) ? feat[(size_t)p4.x * G_C + c] : 0.0f;
    v.y = (p4.y >= 0) ? feat[(size_t)p4.y * G_C + c] : 0.0f;
    v.z = (p4.z >= 0) ? feat[(size_t)p4.z * G_C + c] : 0.0f;
    v.w = (p4.w >= 0) ? feat[(size_t)p4.w * G_C + c] : 0.0f;
    *(float4*)(orow + (size_t)c * G_CELLS) = v;
  }
}

extern "C" void kernel_launch(void* const* d_in, const int* in_sizes, int n_in,
                              void* d_out, int out_size, void* d_ws, size_t ws_size,
                              hipStream_t stream) {
  const float* feat = (const float*)d_in[0];   // [P, 64] fp32
  const int* coords = (const int*)d_in[1];     // [P, 4] int32
  // d_in[2] = batch_size scalar (fixed at 4 for this problem)
  float* out = (float*)d_out;

  const int P = in_sizes[0] / G_C;
  int* map = (int*)d_ws; // B*CELLS int32 = 4 MiB

  // 1) map = -1 everywhere (d_ws is poisoned each call; must re-init)
  hipMemsetAsync(map, 0xFF, (size_t)G_B * G_CELLS * sizeof(int), stream);

  // 2) scatter pillar indices into the map
  ppscatter_map_kernel<<<(P + 255) / 256, 256, 0, stream>>>(coords, map, P);

  // 3) gather: fully coalesced output writes
  ppscatter_gather_kernel<<<dim3(G_CELLS / 1024, G_B), 256, 0, stream>>>(
      feat, map, out);
}

// Round 3
// 297.450 us; speedup vs baseline: 1.0662x; 1.0662x over previous
//
#include <hip/hip_runtime.h>

// PointPillarScatter (B=4, C=64, 512x512x1 grid, P=120000)
// Invert scatter -> gather:
//   1) memset cell->pillar map (d_ws) to -1              (4 MiB)
//   2) scatter: map[b*cells + cell] = p                  (tiny)
//   3) gather: float4 row reads + 4x4 register transpose + nontemporal
//      float4 output stores (all global accesses vectorized/coalesced).

#define G_NX 512
#define G_NY 512
#define G_C 64
#define G_B 4
#define G_CELLS (G_NX * G_NY) // 262144 (nz == 1)

// native clang vector type: __builtin_nontemporal_store requires it
// (HIP's float4 is a struct and is rejected).
typedef float fv4 __attribute__((ext_vector_type(4)));

__global__ __launch_bounds__(256) void ppscatter_map_kernel(
    const int* __restrict__ coords, int* __restrict__ map, int P) {
  int p = blockIdx.x * blockDim.x + threadIdx.x;
  if (p >= P) return;
  int4 cr = ((const int4*)coords)[p]; // [b, z, y, x]
  map[cr.x * G_CELLS + (cr.y + cr.z * G_NX + cr.w)] = p;
}

// grid: (CELLS/1024, B), block 256. Thread owns 4 consecutive cells.
// Per channel-group cg (4 channels): 4x fv4 row loads -> register
// transpose -> 4x fv4 nontemporal stores (4 cells wide each).
__global__ __launch_bounds__(256) void ppscatter_gather_kernel(
    const float* __restrict__ feat, const int* __restrict__ map,
    float* __restrict__ out) {
  const int b = blockIdx.y;
  const int cell0 = blockIdx.x * 1024 + threadIdx.x * 4;

  int4 p4 = *(const int4*)(map + b * G_CELLS + cell0);
  float* orow = out + (size_t)b * (G_C * G_CELLS) + cell0;
  const fv4* f4 = (const fv4*)feat; // row p starts at f4[p*16]

  const long q0 = (long)p4.x * 16, q1 = (long)p4.y * 16;
  const long q2 = (long)p4.z * 16, q3 = (long)p4.w * 16;
  const fv4 z4 = {0.f, 0.f, 0.f, 0.f};

#pragma unroll
  for (int cg = 0; cg < 16; ++cg) {
    fv4 r0 = (p4.x >= 0) ? f4[q0 + cg] : z4;
    fv4 r1 = (p4.y >= 0) ? f4[q1 + cg] : z4;
    fv4 r2 = (p4.z >= 0) ? f4[q2 + cg] : z4;
    fv4 r3 = (p4.w >= 0) ? f4[q3 + cg] : z4;

    fv4 s0 = {r0.x, r1.x, r2.x, r3.x};
    fv4 s1 = {r0.y, r1.y, r2.y, r3.y};
    fv4 s2 = {r0.z, r1.z, r2.z, r3.z};
    fv4 s3 = {r0.w, r1.w, r2.w, r3.w};

    __builtin_nontemporal_store(s0, (fv4*)(orow + (size_t)(4 * cg + 0) * G_CELLS));
    __builtin_nontemporal_store(s1, (fv4*)(orow + (size_t)(4 * cg + 1) * G_CELLS));
    __builtin_nontemporal_store(s2, (fv4*)(orow + (size_t)(4 * cg + 2) * G_CELLS));
    __builtin_nontemporal_store(s3, (fv4*)(orow + (size_t)(4 * cg + 3) * G_CELLS));
  }
}

extern "C" void kernel_launch(void* const* d_in, const int* in_sizes, int n_in,
                              void* d_out, int out_size, void* d_ws, size_t ws_size,
                              hipStream_t stream) {
  const float* feat = (const float*)d_in[0];   // [P, 64] fp32
  const int* coords = (const int*)d_in[1];     // [P, 4] int32
  float* out = (float*)d_out;                  // [4, 64, 512, 512] fp32

  const int P = in_sizes[0] / G_C;
  int* map = (int*)d_ws; // B*CELLS int32 = 4 MiB

  (void)hipMemsetAsync(map, 0xFF, (size_t)G_B * G_CELLS * sizeof(int), stream);
  ppscatter_map_kernel<<<(P + 255) / 256, 256, 0, stream>>>(coords, map, P);
  ppscatter_gather_kernel<<<dim3(G_CELLS / 1024, G_B), 256, 0, stream>>>(
      feat, map, out);
}